// Round 1
// baseline (834.329 us; speedup 1.0000x reference)
//
#include <hip/hip_runtime.h>

#define NN 100000
#define NE 1600000
#define HD 128
#define NL 3
#define NC 40

typedef unsigned int u32;
typedef unsigned short u16;
typedef __attribute__((ext_vector_type(8))) short short8;
typedef __attribute__((ext_vector_type(4))) float f32x4;

__device__ __forceinline__ float b2f(u16 h){
    union{u32 u; float f;} v; v.u = ((u32)h) << 16; return v.f;
}
__device__ __forceinline__ u16 f2b(float f){
    union{float f; u32 u;} v; v.f = f;
    u32 u = v.u;
    u32 r = (u + 0x7FFFu + ((u >> 16) & 1u)) >> 16;
    return (u16)r;
}

// ---------------- conversion kernels ----------------
__global__ void k_conv_x(const float* __restrict__ x, u16* __restrict__ h){
    int i = blockIdx.x * blockDim.x + threadIdx.x;
    const int total = NN * HD / 4;
    if (i >= total) return;
    float4 v = reinterpret_cast<const float4*>(x)[i];
    ushort4 o;
    o.x = f2b(v.x); o.y = f2b(v.y); o.z = f2b(v.z); o.w = f2b(v.w);
    reinterpret_cast<ushort4*>(h)[i] = o;
}

// Wt[l][n][k] = W[l][k][n]  (transposed, bf16)
__global__ void k_conv_w(const float* __restrict__ Ws, u16* __restrict__ wt){
    int i = blockIdx.x * blockDim.x + threadIdx.x;
    if (i >= NL * HD * HD) return;
    int l = i / (HD * HD);
    int r = i % (HD * HD);
    int n = r / HD;
    int k = r % HD;
    wt[i] = f2b(Ws[l * HD * HD + k * HD + n]);
}

// ---------------- graph preprocessing ----------------
__global__ void k_deg(const int* __restrict__ dst, int* __restrict__ cnt){
    int e = blockIdx.x * blockDim.x + threadIdx.x;
    if (e < NE) atomicAdd(&cnt[dst[e]], 1);
}

__global__ void k_dinv(const int* __restrict__ cnt, float* __restrict__ dinv){
    int n = blockIdx.x * blockDim.x + threadIdx.x;
    if (n < NN) dinv[n] = rsqrtf((float)(cnt[n] + 1));
}

// single-block exclusive scan over cnt -> offs, cursor
__global__ void k_scan(const int* __restrict__ cnt, int* __restrict__ offs, int* __restrict__ cursor){
    __shared__ int ws[16];
    __shared__ int btot;
    int tid = threadIdx.x;
    int lane = tid & 63;
    int w = tid >> 6;
    int carry = 0;
    for (int base = 0; base < NN; base += 1024){
        int i = base + tid;
        int v = (i < NN) ? cnt[i] : 0;
        int incl = v;
        #pragma unroll
        for (int d = 1; d < 64; d <<= 1){
            int t = __shfl_up(incl, d);
            if (lane >= d) incl += t;
        }
        if (lane == 63) ws[w] = incl;
        __syncthreads();
        if (tid == 0){
            int run = 0;
            #pragma unroll
            for (int j = 0; j < 16; j++){ int t = ws[j]; ws[j] = run; run += t; }
            btot = run;
        }
        __syncthreads();
        int excl = carry + ws[w] + incl - v;
        if (i < NN){ offs[i] = excl; cursor[i] = excl; }
        carry += btot;
        __syncthreads();
    }
    if (tid == 0) offs[NN] = carry;
}

__global__ void k_fill(const int* __restrict__ src, const int* __restrict__ dst,
                       const float* __restrict__ dinv, int* __restrict__ cursor,
                       int* __restrict__ csr_src, float* __restrict__ csr_norm){
    int e = blockIdx.x * blockDim.x + threadIdx.x;
    if (e >= NE) return;
    int s = src[e], d = dst[e];
    int slot = atomicAdd(&cursor[d], 1);
    csr_src[slot] = s;
    csr_norm[slot] = dinv[s] * dinv[d];
}

// ---------------- dense GEMM: hw = h @ W  (MFMA bf16) ----------------
// block = 256 threads = 4 waves; each wave: 16 rows x 128 cols, K=128
__launch_bounds__(256)
__global__ void k_gemm(const u16* __restrict__ h, const u16* __restrict__ wt, u16* __restrict__ out){
    __shared__ u16 wlds[HD * HD]; // 32KB, XOR-swizzled in 16B units
    int tid = threadIdx.x;
    {
        const uint4* g = reinterpret_cast<const uint4*>(wt);
        #pragma unroll
        for (int i = 0; i < 8; i++){
            int lin16 = tid + 256 * i;          // 0..2047 (16B units)
            uint4 v = g[lin16];
            int c = lin16 >> 4;                 // row of Wt (= output col), 16 units/row
            int addr16 = lin16 ^ (c & 7);
            reinterpret_cast<uint4*>(wlds)[addr16] = v;
        }
    }
    __syncthreads();

    int wv = tid >> 6, lane = tid & 63;
    int row_base = blockIdx.x * 64 + wv * 16;
    int arow = row_base + (lane & 15);
    if (arow >= NN) arow = NN - 1;
    int koff = (lane >> 4) * 8;                 // 0,8,16,24

    f32x4 acc[8];
    #pragma unroll
    for (int t = 0; t < 8; t++) acc[t] = (f32x4){0.f, 0.f, 0.f, 0.f};

    #pragma unroll
    for (int kk = 0; kk < 4; kk++){
        short8 a = *reinterpret_cast<const short8*>(h + arow * HD + kk * 32 + koff);
        #pragma unroll
        for (int ct = 0; ct < 8; ct++){
            int c = ct * 16 + (lane & 15);
            int addr16 = (c * 16 + kk * 4 + (koff >> 3)) ^ (c & 7);
            short8 b = *reinterpret_cast<const short8*>(wlds + addr16 * 8);
            acc[ct] = __builtin_amdgcn_mfma_f32_16x16x32_bf16(a, b, acc[ct], 0, 0, 0);
        }
    }

    int drow = row_base + (lane >> 4) * 4;
    int dcol = lane & 15;
    #pragma unroll
    for (int ct = 0; ct < 8; ct++){
        #pragma unroll
        for (int r = 0; r < 4; r++){
            int rr = drow + r;
            if (rr < NN) out[rr * HD + ct * 16 + dcol] = f2b(acc[ct][r]);
        }
    }
}

// ---------------- aggregation + BN stats ----------------
// wave per node; each lane owns 2 features
__launch_bounds__(256)
__global__ void k_agg(const u16* __restrict__ hw, const int* __restrict__ offs,
                      const int* __restrict__ csr_src, const float* __restrict__ csr_norm,
                      const float* __restrict__ dinv, const float* __restrict__ bias,
                      u16* __restrict__ agg, float* __restrict__ sums){
    __shared__ float redS[4][HD];
    __shared__ float redQ[4][HD];
    int tid = threadIdx.x;
    int lane = tid & 63;
    int wv = tid >> 6;
    int gw = blockIdx.x * 4 + wv;
    int nw = gridDim.x * 4;
    int f0 = lane * 2;
    float b0 = bias[f0], b1 = bias[f0 + 1];
    float s0 = 0.f, s1 = 0.f, q0 = 0.f, q1 = 0.f;

    for (int d = gw; d < NN; d += nw){
        float di = dinv[d];
        float sn = di * di;
        u32 v = *reinterpret_cast<const u32*>(hw + d * HD + f0);
        float a0 = b2f((u16)(v & 0xFFFF)) * sn + b0;
        float a1 = b2f((u16)(v >> 16)) * sn + b1;
        int e = offs[d], e1 = offs[d + 1];
        for (; e + 4 <= e1; e += 4){
            int i0 = csr_src[e], i1 = csr_src[e + 1], i2 = csr_src[e + 2], i3 = csr_src[e + 3];
            float n0 = csr_norm[e], n1 = csr_norm[e + 1], n2 = csr_norm[e + 2], n3 = csr_norm[e + 3];
            u32 v0 = *reinterpret_cast<const u32*>(hw + i0 * HD + f0);
            u32 v1 = *reinterpret_cast<const u32*>(hw + i1 * HD + f0);
            u32 v2 = *reinterpret_cast<const u32*>(hw + i2 * HD + f0);
            u32 v3 = *reinterpret_cast<const u32*>(hw + i3 * HD + f0);
            a0 += b2f((u16)(v0 & 0xFFFF)) * n0; a1 += b2f((u16)(v0 >> 16)) * n0;
            a0 += b2f((u16)(v1 & 0xFFFF)) * n1; a1 += b2f((u16)(v1 >> 16)) * n1;
            a0 += b2f((u16)(v2 & 0xFFFF)) * n2; a1 += b2f((u16)(v2 >> 16)) * n2;
            a0 += b2f((u16)(v3 & 0xFFFF)) * n3; a1 += b2f((u16)(v3 >> 16)) * n3;
        }
        for (; e < e1; e++){
            int s = csr_src[e];
            float nm = csr_norm[e];
            u32 vv = *reinterpret_cast<const u32*>(hw + s * HD + f0);
            a0 += b2f((u16)(vv & 0xFFFF)) * nm;
            a1 += b2f((u16)(vv >> 16)) * nm;
        }
        u32 o = ((u32)f2b(a1) << 16) | (u32)f2b(a0);
        *reinterpret_cast<u32*>(agg + d * HD + f0) = o;
        s0 += a0; s1 += a1; q0 += a0 * a0; q1 += a1 * a1;
    }

    redS[wv][f0] = s0; redS[wv][f0 + 1] = s1;
    redQ[wv][f0] = q0; redQ[wv][f0 + 1] = q1;
    __syncthreads();
    if (tid < HD){
        float ts = redS[0][tid] + redS[1][tid] + redS[2][tid] + redS[3][tid];
        float tq = redQ[0][tid] + redQ[1][tid] + redQ[2][tid] + redQ[3][tid];
        atomicAdd(&sums[tid], ts);
        atomicAdd(&sums[HD + tid], tq);
    }
}

__global__ void k_bnprep(const float* __restrict__ sums, const float* __restrict__ gamma,
                         const float* __restrict__ beta, float* __restrict__ bn){
    int f = threadIdx.x;
    if (f >= HD) return;
    float mu = sums[f] / (float)NN;
    float var = sums[HD + f] / (float)NN - mu * mu;
    float inv = rsqrtf(var + 1e-5f);
    float a = gamma[f] * inv;
    bn[f] = a;
    bn[HD + f] = beta[f] - mu * a;
}

__global__ void k_bnapply(const u16* __restrict__ agg, const float* __restrict__ bn,
                          u16* __restrict__ hout){
    int i = blockIdx.x * blockDim.x + threadIdx.x;
    const int total = NN * HD / 2;
    if (i >= total) return;
    int f0 = (i * 2) & (HD - 1);
    u32 v = reinterpret_cast<const u32*>(agg)[i];
    float a0 = bn[f0], a1 = bn[f0 + 1];
    float c0 = bn[HD + f0], c1 = bn[HD + f0 + 1];
    float x0 = b2f((u16)(v & 0xFFFF)) * a0 + c0;
    float x1 = b2f((u16)(v >> 16)) * a1 + c1;
    reinterpret_cast<u32*>(hout)[i] = ((u32)f2b(x1) << 16) | (u32)f2b(x0);
}

// ---------------- output head: out (+)= h @ W_out[row0:row0+128] ----------------
__launch_bounds__(256)
__global__ void k_head(const u16* __restrict__ h, const float* __restrict__ wout,
                       const float* __restrict__ bout, float* __restrict__ out,
                       int row0, int first){
    __shared__ float wl[HD * NC]; // 20KB
    __shared__ float bl[NC];
    int tid = threadIdx.x;
    for (int i = tid; i < HD * NC; i += 256) wl[i] = wout[row0 * NC + i];
    if (tid < NC) bl[tid] = bout[tid];
    __syncthreads();
    int n = blockIdx.x * 256 + tid;
    if (n >= NN) return;
    float acc[NC];
    if (first){
        #pragma unroll
        for (int j = 0; j < NC; j++) acc[j] = bl[j];
    } else {
        #pragma unroll
        for (int j = 0; j < NC; j++) acc[j] = out[(size_t)n * NC + j];
    }
    const u16* hp = h + (size_t)n * HD;
    #pragma unroll
    for (int k8 = 0; k8 < HD / 8; k8++){
        uint4 v = reinterpret_cast<const uint4*>(hp)[k8];
        const u16* pv = reinterpret_cast<const u16*>(&v);
        #pragma unroll
        for (int t = 0; t < 8; t++){
            float hv = b2f(pv[t]);
            const float* wr = &wl[(k8 * 8 + t) * NC];
            #pragma unroll
            for (int j = 0; j < NC; j++) acc[j] += hv * wr[j];
        }
    }
    #pragma unroll
    for (int j = 0; j < NC; j++) out[(size_t)n * NC + j] = acc[j];
}

// ---------------- launch ----------------
extern "C" void kernel_launch(void* const* d_in, const int* in_sizes, int n_in,
                              void* d_out, int out_size, void* d_ws, size_t ws_size,
                              hipStream_t stream){
    const float* x      = (const float*)d_in[0];
    const float* Ws     = (const float*)d_in[1];
    const float* bs     = (const float*)d_in[2];
    const float* gammas = (const float*)d_in[3];
    const float* betas  = (const float*)d_in[4];
    const float* W_out  = (const float*)d_in[5];
    const float* b_out  = (const float*)d_in[6];
    const int*   ei     = (const int*)d_in[7];
    const int* src = ei;
    const int* dst = ei + NE;
    float* out = (float*)d_out;

    char* ws = (char*)d_ws;
    size_t off = 0;
    auto alloc = [&](size_t bytes) -> char* {
        char* p = ws + off;
        off += (bytes + 255) & ~(size_t)255;
        return p;
    };
    u16*   hA       = (u16*)alloc((size_t)NN * HD * 2);
    u16*   hw       = (u16*)alloc((size_t)NN * HD * 2);
    u16*   aggb     = (u16*)alloc((size_t)NN * HD * 2);
    u16*   wt       = (u16*)alloc((size_t)NL * HD * HD * 2);
    int*   cnt      = (int*)alloc((size_t)NN * 4);
    float* dinv     = (float*)alloc((size_t)NN * 4);
    int*   offs     = (int*)alloc((size_t)(NN + 1) * 4);
    int*   cursor   = (int*)alloc((size_t)NN * 4);
    int*   csr_src  = (int*)alloc((size_t)NE * 4);
    float* csr_norm = (float*)alloc((size_t)NE * 4);
    float* stats    = (float*)alloc((size_t)NL * 2 * HD * 4);
    float* bn       = (float*)alloc((size_t)2 * HD * 4);

    hipMemsetAsync(cnt, 0, (size_t)NN * 4, stream);
    hipMemsetAsync(stats, 0, (size_t)NL * 2 * HD * 4, stream);

    k_conv_x<<<(NN * HD / 4 + 255) / 256, 256, 0, stream>>>(x, hA);
    k_conv_w<<<(NL * HD * HD + 255) / 256, 256, 0, stream>>>(Ws, wt);
    k_deg<<<(NE + 255) / 256, 256, 0, stream>>>(dst, cnt);
    k_dinv<<<(NN + 255) / 256, 256, 0, stream>>>(cnt, dinv);
    k_scan<<<1, 1024, 0, stream>>>(cnt, offs, cursor);
    k_fill<<<(NE + 255) / 256, 256, 0, stream>>>(src, dst, dinv, cursor, csr_src, csr_norm);

    k_head<<<(NN + 255) / 256, 256, 0, stream>>>(hA, W_out, b_out, out, 0, 1);

    for (int l = 0; l < NL; l++){
        k_gemm<<<(NN + 63) / 64, 256, 0, stream>>>(hA, wt + (size_t)l * HD * HD, hw);
        k_agg<<<2048, 256, 0, stream>>>(hw, offs, csr_src, csr_norm, dinv,
                                        bs + (size_t)l * HD, aggb, stats + (size_t)l * 2 * HD);
        k_bnprep<<<1, 128, 0, stream>>>(stats + (size_t)l * 2 * HD,
                                        gammas + (size_t)l * HD, betas + (size_t)l * HD, bn);
        k_bnapply<<<(NN * HD / 2 + 255) / 256, 256, 0, stream>>>(aggb, bn, hA);
        k_head<<<(NN + 255) / 256, 256, 0, stream>>>(hA, W_out, b_out, out, HD + l * HD, 0);
    }
}

// Round 2
// 768.161 us; speedup vs baseline: 1.0861x; 1.0861x over previous
//
#include <hip/hip_runtime.h>

#define NN 100000
#define NE 1600000
#define HD 128
#define NL 3
#define NC 40
#define NB 98   // scan blocks: 98*1024 >= NN

typedef unsigned int u32;
typedef unsigned short u16;
typedef __attribute__((ext_vector_type(8))) short short8;
typedef __attribute__((ext_vector_type(4))) float f32x4;

__device__ __forceinline__ float b2f(u16 h){
    union{u32 u; float f;} v; v.u = ((u32)h) << 16; return v.f;
}
__device__ __forceinline__ u16 f2b(float f){
    union{float f; u32 u;} v; v.f = f;
    u32 u = v.u;
    u32 r = (u + 0x7FFFu + ((u >> 16) & 1u)) >> 16;
    return (u16)r;
}

// ---------------- weight conversion ----------------
// Wt[l][n][k] = W[l][k][n]  (transposed, bf16)
__global__ void k_conv_w(const float* __restrict__ Ws, u16* __restrict__ wt){
    int i = blockIdx.x * blockDim.x + threadIdx.x;
    if (i >= NL * HD * HD) return;
    int l = i / (HD * HD);
    int r = i % (HD * HD);
    int n = r / HD;
    int k = r % HD;
    wt[i] = f2b(Ws[l * HD * HD + k * HD + n]);
}

// ---------------- x -> bf16 + first head pass: out = b_out + x @ W_out[0:128] ----------------
__launch_bounds__(256)
__global__ void k_convhead(const float* __restrict__ x, const float* __restrict__ wout,
                           const float* __restrict__ bout, float* __restrict__ out,
                           u16* __restrict__ hA){
    __shared__ float wl[HD * NC]; // rows 0..127 of W_out
    __shared__ float bl[NC];
    int tid = threadIdx.x;
    for (int i = tid; i < HD * NC; i += 256) wl[i] = wout[i];
    if (tid < NC) bl[tid] = bout[tid];
    __syncthreads();
    int n = blockIdx.x * 256 + tid;
    if (n >= NN) return;
    f32x4 acc[10];
    #pragma unroll
    for (int q = 0; q < 10; q++) acc[q] = *reinterpret_cast<const f32x4*>(&bl[q * 4]);
    const float* xr = x + (size_t)n * HD;
    #pragma unroll
    for (int k8 = 0; k8 < HD / 8; k8++){
        float4 v0 = reinterpret_cast<const float4*>(xr)[k8 * 2];
        float4 v1 = reinterpret_cast<const float4*>(xr)[k8 * 2 + 1];
        float xs[8] = {v0.x, v0.y, v0.z, v0.w, v1.x, v1.y, v1.z, v1.w};
        uint4 ov;
        u16* po = (u16*)&ov;
        #pragma unroll
        for (int t = 0; t < 8; t++){
            int f = k8 * 8 + t;
            po[t] = f2b(xs[t]);
            const f32x4* wr = reinterpret_cast<const f32x4*>(&wl[f * NC]);
            #pragma unroll
            for (int q = 0; q < 10; q++) acc[q] += xs[t] * wr[q];
        }
        reinterpret_cast<uint4*>(hA + (size_t)n * HD)[k8] = ov;
    }
    float* orw = out + (size_t)n * NC;
    #pragma unroll
    for (int q = 0; q < 10; q++) reinterpret_cast<f32x4*>(orw)[q] = acc[q];
}

// ---------------- graph preprocessing ----------------
__global__ void k_deg(const int* __restrict__ dst, int* __restrict__ cnt){
    int e = blockIdx.x * blockDim.x + threadIdx.x;
    if (e < NE) atomicAdd(&cnt[dst[e]], 1);
}

// multi-block scan, stage 1: block-local exclusive scan + block totals + dinv
__launch_bounds__(1024)
__global__ void k_scan1(const int* __restrict__ cnt, int* __restrict__ offs,
                        int* __restrict__ partials, float* __restrict__ dinv){
    __shared__ int ws[16];
    int tid = threadIdx.x, lane = tid & 63, w = tid >> 6;
    int i = blockIdx.x * 1024 + tid;
    int v = (i < NN) ? cnt[i] : 0;
    if (i < NN) dinv[i] = rsqrtf((float)(v + 1));
    int incl = v;
    #pragma unroll
    for (int d = 1; d < 64; d <<= 1){
        int t = __shfl_up(incl, d);
        if (lane >= d) incl += t;
    }
    if (lane == 63) ws[w] = incl;
    __syncthreads();
    if (tid == 0){
        int run = 0;
        #pragma unroll
        for (int j = 0; j < 16; j++){ int t = ws[j]; ws[j] = run; run += t; }
        partials[blockIdx.x] = run;
    }
    __syncthreads();
    int excl = ws[w] + incl - v;
    if (i < NN) offs[i] = excl;
}

// stage 2: exclusive scan of the 98 block totals (in place)
__global__ void k_scan2(int* __restrict__ partials){
    __shared__ int tot0;
    int tid = threadIdx.x, lane = tid & 63, w = tid >> 6;
    int v = (tid < NB) ? partials[tid] : 0;
    int incl = v;
    #pragma unroll
    for (int d = 1; d < 64; d <<= 1){
        int t = __shfl_up(incl, d);
        if (lane >= d) incl += t;
    }
    if (w == 0 && lane == 63) tot0 = incl;
    __syncthreads();
    int excl = incl - v + (w == 1 ? tot0 : 0);
    if (tid < NB) partials[tid] = excl;
}

// stage 3: add block prefix, write final offs + cursor
__global__ void k_scan3(int* __restrict__ offs, const int* __restrict__ partials,
                        int* __restrict__ cursor){
    int i = blockIdx.x * blockDim.x + threadIdx.x;
    if (i < NN){
        int o = offs[i] + partials[i >> 10];
        offs[i] = o;
        cursor[i] = o;
    }
    if (i == 0) offs[NN] = NE;
}

__global__ void k_fill(const int* __restrict__ src, const int* __restrict__ dst,
                       int* __restrict__ cursor, int* __restrict__ csr_src){
    int e = blockIdx.x * blockDim.x + threadIdx.x;
    if (e >= NE) return;
    int s = src[e], d = dst[e];
    int slot = atomicAdd(&cursor[d], 1);
    csr_src[slot] = s;
}

// ---------------- dense GEMM: hw = (h @ W) * dinv[row]  (MFMA bf16) ----------------
__launch_bounds__(256)
__global__ void k_gemm(const u16* __restrict__ h, const u16* __restrict__ wt,
                       const float* __restrict__ dinv, u16* __restrict__ out){
    __shared__ u16 wlds[HD * HD]; // 32KB, XOR-swizzled in 16B units
    int tid = threadIdx.x;
    {
        const uint4* g = reinterpret_cast<const uint4*>(wt);
        #pragma unroll
        for (int i = 0; i < 8; i++){
            int lin16 = tid + 256 * i;
            uint4 v = g[lin16];
            int c = lin16 >> 4;
            int addr16 = lin16 ^ (c & 7);
            reinterpret_cast<uint4*>(wlds)[addr16] = v;
        }
    }
    __syncthreads();

    int wv = tid >> 6, lane = tid & 63;
    int row_base = blockIdx.x * 64 + wv * 16;
    int arow = row_base + (lane & 15);
    if (arow >= NN) arow = NN - 1;
    int koff = (lane >> 4) * 8;

    f32x4 acc[8];
    #pragma unroll
    for (int t = 0; t < 8; t++) acc[t] = (f32x4){0.f, 0.f, 0.f, 0.f};

    #pragma unroll
    for (int kk = 0; kk < 4; kk++){
        short8 a = *reinterpret_cast<const short8*>(h + arow * HD + kk * 32 + koff);
        #pragma unroll
        for (int ct = 0; ct < 8; ct++){
            int c = ct * 16 + (lane & 15);
            int addr16 = (c * 16 + kk * 4 + (koff >> 3)) ^ (c & 7);
            short8 b = *reinterpret_cast<const short8*>(wlds + addr16 * 8);
            acc[ct] = __builtin_amdgcn_mfma_f32_16x16x32_bf16(a, b, acc[ct], 0, 0, 0);
        }
    }

    int drow = row_base + (lane >> 4) * 4;
    int dcol = lane & 15;
    float dv[4];
    #pragma unroll
    for (int r = 0; r < 4; r++){
        int rr = drow + r;
        dv[r] = dinv[rr < NN ? rr : NN - 1];
    }
    #pragma unroll
    for (int ct = 0; ct < 8; ct++){
        #pragma unroll
        for (int r = 0; r < 4; r++){
            int rr = drow + r;
            if (rr < NN) out[rr * HD + ct * 16 + dcol] = f2b(acc[ct][r] * dv[r]);
        }
    }
}

// ---------------- aggregation + BN stats ----------------
// wave per node; each lane owns 2 features
// agg[d] = dinv[d] * (sum_{s in N(d)} hw_s[s] + hw_s[d]) + bias
__launch_bounds__(256)
__global__ void k_agg(const u16* __restrict__ hw, const int* __restrict__ offs,
                      const int* __restrict__ csr_src, const float* __restrict__ dinv,
                      const float* __restrict__ bias,
                      u16* __restrict__ agg, float* __restrict__ sums){
    __shared__ float redS[4][HD];
    __shared__ float redQ[4][HD];
    int tid = threadIdx.x;
    int lane = tid & 63;
    int wv = tid >> 6;
    int gw = blockIdx.x * 4 + wv;
    int nw = gridDim.x * 4;
    int f0 = lane * 2;
    float b0 = bias[f0], b1 = bias[f0 + 1];
    float s0 = 0.f, s1 = 0.f, q0 = 0.f, q1 = 0.f;

    for (int d = gw; d < NN; d += nw){
        float di = dinv[d];
        u32 v = *reinterpret_cast<const u32*>(hw + d * HD + f0);
        float a0 = b2f((u16)(v & 0xFFFF));
        float a1 = b2f((u16)(v >> 16));
        int e = offs[d], e1 = offs[d + 1];
        for (; e + 4 <= e1; e += 4){
            int i0 = csr_src[e], i1 = csr_src[e + 1], i2 = csr_src[e + 2], i3 = csr_src[e + 3];
            u32 v0 = *reinterpret_cast<const u32*>(hw + i0 * HD + f0);
            u32 v1 = *reinterpret_cast<const u32*>(hw + i1 * HD + f0);
            u32 v2 = *reinterpret_cast<const u32*>(hw + i2 * HD + f0);
            u32 v3 = *reinterpret_cast<const u32*>(hw + i3 * HD + f0);
            a0 += b2f((u16)(v0 & 0xFFFF)); a1 += b2f((u16)(v0 >> 16));
            a0 += b2f((u16)(v1 & 0xFFFF)); a1 += b2f((u16)(v1 >> 16));
            a0 += b2f((u16)(v2 & 0xFFFF)); a1 += b2f((u16)(v2 >> 16));
            a0 += b2f((u16)(v3 & 0xFFFF)); a1 += b2f((u16)(v3 >> 16));
        }
        for (; e < e1; e++){
            int s = csr_src[e];
            u32 vv = *reinterpret_cast<const u32*>(hw + s * HD + f0);
            a0 += b2f((u16)(vv & 0xFFFF));
            a1 += b2f((u16)(vv >> 16));
        }
        a0 = a0 * di + b0;
        a1 = a1 * di + b1;
        u32 o = ((u32)f2b(a1) << 16) | (u32)f2b(a0);
        *reinterpret_cast<u32*>(agg + d * HD + f0) = o;
        s0 += a0; s1 += a1; q0 += a0 * a0; q1 += a1 * a1;
    }

    redS[wv][f0] = s0; redS[wv][f0 + 1] = s1;
    redQ[wv][f0] = q0; redQ[wv][f0 + 1] = q1;
    __syncthreads();
    if (tid < HD){
        float ts = redS[0][tid] + redS[1][tid] + redS[2][tid] + redS[3][tid];
        float tq = redQ[0][tid] + redQ[1][tid] + redQ[2][tid] + redQ[3][tid];
        atomicAdd(&sums[tid], ts);
        atomicAdd(&sums[HD + tid], tq);
    }
}

__global__ void k_bnprep(const float* __restrict__ sums, const float* __restrict__ gamma,
                         const float* __restrict__ beta, float* __restrict__ bn){
    int f = threadIdx.x;
    if (f >= HD) return;
    float mu = sums[f] / (float)NN;
    float var = sums[HD + f] / (float)NN - mu * mu;
    float inv = rsqrtf(var + 1e-5f);
    float a = gamma[f] * inv;
    bn[f] = a;
    bn[HD + f] = beta[f] - mu * a;
}

// ---------------- fused BN-apply + head: hA = BN(agg); out += hA @ W_out[row0:row0+128] ----------------
__launch_bounds__(256)
__global__ void k_bnhead(const u16* __restrict__ agg, const float* __restrict__ bn,
                         const float* __restrict__ wout, float* __restrict__ out,
                         u16* __restrict__ hA, int row0){
    __shared__ float wl[HD * NC]; // 20KB
    __shared__ float A[HD];
    __shared__ float C[HD];
    int tid = threadIdx.x;
    for (int i = tid; i < HD * NC; i += 256) wl[i] = wout[row0 * NC + i];
    if (tid < HD){ A[tid] = bn[tid]; C[tid] = bn[HD + tid]; }
    __syncthreads();
    int n = blockIdx.x * 256 + tid;
    if (n >= NN) return;
    float* orw = out + (size_t)n * NC;
    f32x4 acc[10];
    #pragma unroll
    for (int q = 0; q < 10; q++) acc[q] = reinterpret_cast<const f32x4*>(orw)[q];
    #pragma unroll
    for (int k8 = 0; k8 < HD / 8; k8++){
        uint4 v = reinterpret_cast<const uint4*>(agg + (size_t)n * HD)[k8];
        const u16* pv = (const u16*)&v;
        uint4 ov;
        u16* po = (u16*)&ov;
        #pragma unroll
        for (int t = 0; t < 8; t++){
            int f = k8 * 8 + t;
            float xv = b2f(pv[t]) * A[f] + C[f];
            po[t] = f2b(xv);
            const f32x4* wr = reinterpret_cast<const f32x4*>(&wl[f * NC]);
            #pragma unroll
            for (int q = 0; q < 10; q++) acc[q] += xv * wr[q];
        }
        reinterpret_cast<uint4*>(hA + (size_t)n * HD)[k8] = ov;
    }
    #pragma unroll
    for (int q = 0; q < 10; q++) reinterpret_cast<f32x4*>(orw)[q] = acc[q];
}

// ---------------- launch ----------------
extern "C" void kernel_launch(void* const* d_in, const int* in_sizes, int n_in,
                              void* d_out, int out_size, void* d_ws, size_t ws_size,
                              hipStream_t stream){
    const float* x      = (const float*)d_in[0];
    const float* Ws     = (const float*)d_in[1];
    const float* bs     = (const float*)d_in[2];
    const float* gammas = (const float*)d_in[3];
    const float* betas  = (const float*)d_in[4];
    const float* W_out  = (const float*)d_in[5];
    const float* b_out  = (const float*)d_in[6];
    const int*   ei     = (const int*)d_in[7];
    const int* src = ei;
    const int* dst = ei + NE;
    float* out = (float*)d_out;

    char* ws = (char*)d_ws;
    size_t off = 0;
    auto alloc = [&](size_t bytes) -> char* {
        char* p = ws + off;
        off += (bytes + 255) & ~(size_t)255;
        return p;
    };
    u16*   hA       = (u16*)alloc((size_t)NN * HD * 2);
    u16*   hw       = (u16*)alloc((size_t)NN * HD * 2);
    u16*   aggb     = (u16*)alloc((size_t)NN * HD * 2);
    u16*   wt       = (u16*)alloc((size_t)NL * HD * HD * 2);
    int*   cnt      = (int*)alloc((size_t)NN * 4);
    float* dinv     = (float*)alloc((size_t)NN * 4);
    int*   offs     = (int*)alloc((size_t)(NN + 1) * 4);
    int*   cursor   = (int*)alloc((size_t)NN * 4);
    int*   partials = (int*)alloc((size_t)NB * 4);
    int*   csr_src  = (int*)alloc((size_t)NE * 4);
    float* stats    = (float*)alloc((size_t)NL * 2 * HD * 4);
    float* bn       = (float*)alloc((size_t)2 * HD * 4);

    hipMemsetAsync(cnt, 0, (size_t)NN * 4, stream);
    hipMemsetAsync(stats, 0, (size_t)NL * 2 * HD * 4, stream);

    k_conv_w<<<(NL * HD * HD + 255) / 256, 256, 0, stream>>>(Ws, wt);
    k_deg<<<(NE + 255) / 256, 256, 0, stream>>>(dst, cnt);
    k_scan1<<<NB, 1024, 0, stream>>>(cnt, offs, partials, dinv);
    k_scan2<<<1, 128, 0, stream>>>(partials);
    k_scan3<<<(NN + 1023) / 1024, 1024, 0, stream>>>(offs, partials, cursor);
    k_fill<<<(NE + 255) / 256, 256, 0, stream>>>(src, dst, cursor, csr_src);

    k_convhead<<<(NN + 255) / 256, 256, 0, stream>>>(x, W_out, b_out, out, hA);

    for (int l = 0; l < NL; l++){
        k_gemm<<<(NN + 63) / 64, 256, 0, stream>>>(hA, wt + (size_t)l * HD * HD, dinv, hw);
        k_agg<<<2048, 256, 0, stream>>>(hw, offs, csr_src, dinv,
                                        bs + (size_t)l * HD, aggb, stats + (size_t)l * 2 * HD);
        k_bnprep<<<1, 128, 0, stream>>>(stats + (size_t)l * 2 * HD,
                                        gammas + (size_t)l * HD, betas + (size_t)l * HD, bn);
        k_bnhead<<<(NN + 255) / 256, 256, 0, stream>>>(aggb, bn, W_out, out, hA,
                                                       HD + l * HD);
    }
}

// Round 3
// 605.963 us; speedup vs baseline: 1.3769x; 1.2677x over previous
//
#include <hip/hip_runtime.h>

#define NN 100000
#define NE 1600000
#define HD 128
#define NL 3
#define NC 40

#define NBK 196     // dst buckets (512 nodes each; 196*512 = 100352 >= NN)
#define NPB 512     // nodes per bucket
#define BSH 9       // bucket shift (dst >> 9)
#define CAP 9216    // per-bucket edge capacity (mean 8192, +11 sigma)
#define EPB 2000    // edges per bin block
#define NBINBLK 800 // 800 * 2000 = NE

typedef unsigned int u32;
typedef unsigned short u16;
typedef __attribute__((ext_vector_type(8))) short short8;
typedef __attribute__((ext_vector_type(4))) float f32x4;

__device__ __forceinline__ float b2f(u16 h){
    union{u32 u; float f;} v; v.u = ((u32)h) << 16; return v.f;
}
__device__ __forceinline__ u16 f2b(float f){
    union{float f; u32 u;} v; v.f = f;
    u32 u = v.u;
    u32 r = (u + 0x7FFFu + ((u >> 16) & 1u)) >> 16;
    return (u16)r;
}

// ---------------- weight conversion ----------------
// Wt[l][n][k] = W[l][k][n]  (transposed, bf16)
__global__ void k_conv_w(const float* __restrict__ Ws, u16* __restrict__ wt){
    int i = blockIdx.x * blockDim.x + threadIdx.x;
    if (i >= NL * HD * HD) return;
    int l = i / (HD * HD);
    int r = i % (HD * HD);
    int n = r / HD;
    int k = r % HD;
    wt[i] = f2b(Ws[l * HD * HD + k * HD + n]);
}

// ---------------- x -> bf16 + first head pass: out = b_out + x @ W_out[0:128] ----------------
__launch_bounds__(256)
__global__ void k_convhead(const float* __restrict__ x, const float* __restrict__ wout,
                           const float* __restrict__ bout, float* __restrict__ out,
                           u16* __restrict__ hA){
    __shared__ float wl[HD * NC]; // rows 0..127 of W_out
    __shared__ float bl[NC];
    int tid = threadIdx.x;
    for (int i = tid; i < HD * NC; i += 256) wl[i] = wout[i];
    if (tid < NC) bl[tid] = bout[tid];
    __syncthreads();
    int n = blockIdx.x * 256 + tid;
    if (n >= NN) return;
    f32x4 acc[10];
    #pragma unroll
    for (int q = 0; q < 10; q++) acc[q] = *reinterpret_cast<const f32x4*>(&bl[q * 4]);
    const float* xr = x + (size_t)n * HD;
    #pragma unroll
    for (int k8 = 0; k8 < HD / 8; k8++){
        float4 v0 = reinterpret_cast<const float4*>(xr)[k8 * 2];
        float4 v1 = reinterpret_cast<const float4*>(xr)[k8 * 2 + 1];
        float xs[8] = {v0.x, v0.y, v0.z, v0.w, v1.x, v1.y, v1.z, v1.w};
        uint4 ov;
        u16* po = (u16*)&ov;
        #pragma unroll
        for (int t = 0; t < 8; t++){
            int f = k8 * 8 + t;
            po[t] = f2b(xs[t]);
            const f32x4* wr = reinterpret_cast<const f32x4*>(&wl[f * NC]);
            #pragma unroll
            for (int q = 0; q < 10; q++) acc[q] += xs[t] * wr[q];
        }
        reinterpret_cast<uint4*>(hA + (size_t)n * HD)[k8] = ov;
    }
    float* orw = out + (size_t)n * NC;
    #pragma unroll
    for (int q = 0; q < 10; q++) reinterpret_cast<f32x4*>(orw)[q] = acc[q];
}

// ---------------- pass 1: bin edges by dst bucket, coalesced grouped writes ----------------
__launch_bounds__(256)
__global__ void k_bin(const int* __restrict__ src, const int* __restrict__ dst,
                      int* __restrict__ gcur, uint2* __restrict__ bb){
    __shared__ int hist[NBK];
    __shared__ int lbase[NBK];
    __shared__ int gbase[NBK];
    __shared__ int cur[NBK];
    __shared__ uint2 stage[EPB]; // 16 KB
    int tid = threadIdx.x;
    int e0 = blockIdx.x * EPB;
    for (int i = tid; i < NBK; i += 256) hist[i] = 0;
    __syncthreads();
    for (int k = tid; k < EPB; k += 256){
        int d = dst[e0 + k];
        atomicAdd(&hist[d >> BSH], 1);
    }
    __syncthreads();
    if (tid == 0){
        int run = 0;
        for (int b = 0; b < NBK; b++){ lbase[b] = run; cur[b] = run; run += hist[b]; }
    }
    __syncthreads();
    if (tid < NBK) gbase[tid] = atomicAdd(&gcur[tid], hist[tid]);
    __syncthreads();
    for (int k = tid; k < EPB; k += 256){
        int s = src[e0 + k], d = dst[e0 + k];
        int pos = atomicAdd(&cur[d >> BSH], 1);
        stage[pos] = make_uint2((u32)s, (u32)d);
    }
    __syncthreads();
    for (int k = tid; k < EPB; k += 256){
        uint2 sd = stage[k];
        int b = (int)(sd.y >> BSH);
        int g = gbase[b] + (k - lbase[b]);
        if (g < CAP) bb[(size_t)b * CAP + g] = sd;
    }
}

// ---------------- scan of bucket totals ----------------
__global__ void k_bscan(const int* __restrict__ gcur, int* __restrict__ ebase,
                        int* __restrict__ offs){
    if (threadIdx.x == 0){
        int run = 0;
        for (int b = 0; b < NBK; b++){ ebase[b] = run; run += (gcur[b] < CAP ? gcur[b] : CAP); }
        offs[NN] = run;
    }
}

// ---------------- pass 2: per-bucket CSR build, all global I/O coalesced ----------------
__launch_bounds__(512)
__global__ void k_csr(const int* __restrict__ gcur, const int* __restrict__ ebase,
                      const uint2* __restrict__ bb, int* __restrict__ csr_src,
                      int* __restrict__ offs, float* __restrict__ dinv){
    __shared__ int hist[NPB];
    __shared__ int cur[NPB];
    __shared__ int wsum[8];
    __shared__ int lcsr[CAP]; // 36 KB
    int tid = threadIdx.x;
    int b = blockIdx.x;
    int cnt_b = gcur[b]; if (cnt_b > CAP) cnt_b = CAP;
    int base = ebase[b];
    const uint2* eb = bb + (size_t)b * CAP;
    hist[tid] = 0;
    __syncthreads();
    for (int k = tid; k < cnt_b; k += 512)
        atomicAdd(&hist[eb[k].y & (NPB - 1)], 1);
    __syncthreads();
    int v = hist[tid];
    int lane = tid & 63, w = tid >> 6;
    int incl = v;
    #pragma unroll
    for (int dlt = 1; dlt < 64; dlt <<= 1){
        int t = __shfl_up(incl, dlt);
        if (lane >= dlt) incl += t;
    }
    if (lane == 63) wsum[w] = incl;
    __syncthreads();
    if (tid == 0){
        int run = 0;
        #pragma unroll
        for (int j = 0; j < 8; j++){ int t = wsum[j]; wsum[j] = run; run += t; }
    }
    __syncthreads();
    int excl = wsum[w] + incl - v;
    int n = b * NPB + tid;
    if (n < NN){
        offs[n] = base + excl;
        dinv[n] = rsqrtf((float)(v + 1));
    }
    cur[tid] = excl;
    __syncthreads();
    for (int k = tid; k < cnt_b; k += 512){
        uint2 sd = eb[k];
        int pos = atomicAdd(&cur[sd.y & (NPB - 1)], 1);
        lcsr[pos] = (int)sd.x;
    }
    __syncthreads();
    for (int k = tid; k < cnt_b; k += 512)
        csr_src[base + k] = lcsr[k];
}

// ---------------- dense GEMM: hw = (h @ W) * dinv[row]  (MFMA bf16) ----------------
__launch_bounds__(256)
__global__ void k_gemm(const u16* __restrict__ h, const u16* __restrict__ wt,
                       const float* __restrict__ dinv, u16* __restrict__ out){
    __shared__ u16 wlds[HD * HD]; // 32KB, XOR-swizzled in 16B units
    int tid = threadIdx.x;
    {
        const uint4* g = reinterpret_cast<const uint4*>(wt);
        #pragma unroll
        for (int i = 0; i < 8; i++){
            int lin16 = tid + 256 * i;
            uint4 v = g[lin16];
            int c = lin16 >> 4;
            int addr16 = lin16 ^ (c & 7);
            reinterpret_cast<uint4*>(wlds)[addr16] = v;
        }
    }
    __syncthreads();

    int wv = tid >> 6, lane = tid & 63;
    int row_base = blockIdx.x * 64 + wv * 16;
    int arow = row_base + (lane & 15);
    if (arow >= NN) arow = NN - 1;
    int koff = (lane >> 4) * 8;

    f32x4 acc[8];
    #pragma unroll
    for (int t = 0; t < 8; t++) acc[t] = (f32x4){0.f, 0.f, 0.f, 0.f};

    #pragma unroll
    for (int kk = 0; kk < 4; kk++){
        short8 a = *reinterpret_cast<const short8*>(h + arow * HD + kk * 32 + koff);
        #pragma unroll
        for (int ct = 0; ct < 8; ct++){
            int c = ct * 16 + (lane & 15);
            int addr16 = (c * 16 + kk * 4 + (koff >> 3)) ^ (c & 7);
            short8 b = *reinterpret_cast<const short8*>(wlds + addr16 * 8);
            acc[ct] = __builtin_amdgcn_mfma_f32_16x16x32_bf16(a, b, acc[ct], 0, 0, 0);
        }
    }

    int drow = row_base + (lane >> 4) * 4;
    int dcol = lane & 15;
    float dv[4];
    #pragma unroll
    for (int r = 0; r < 4; r++){
        int rr = drow + r;
        dv[r] = dinv[rr < NN ? rr : NN - 1];
    }
    #pragma unroll
    for (int ct = 0; ct < 8; ct++){
        #pragma unroll
        for (int r = 0; r < 4; r++){
            int rr = drow + r;
            if (rr < NN) out[rr * HD + ct * 16 + dcol] = f2b(acc[ct][r] * dv[r]);
        }
    }
}

// ---------------- aggregation + BN stats ----------------
// wave per node; each lane owns 2 features
// agg[d] = dinv[d] * (sum_{s in N(d)} hw_s[s] + hw_s[d]) + bias
__launch_bounds__(256)
__global__ void k_agg(const u16* __restrict__ hw, const int* __restrict__ offs,
                      const int* __restrict__ csr_src, const float* __restrict__ dinv,
                      const float* __restrict__ bias,
                      u16* __restrict__ agg, float* __restrict__ sums){
    __shared__ float redS[4][HD];
    __shared__ float redQ[4][HD];
    int tid = threadIdx.x;
    int lane = tid & 63;
    int wv = tid >> 6;
    int gw = blockIdx.x * 4 + wv;
    int nw = gridDim.x * 4;
    int f0 = lane * 2;
    float b0 = bias[f0], b1 = bias[f0 + 1];
    float s0 = 0.f, s1 = 0.f, q0 = 0.f, q1 = 0.f;

    for (int d = gw; d < NN; d += nw){
        float di = dinv[d];
        u32 v = *reinterpret_cast<const u32*>(hw + d * HD + f0);
        float a0 = b2f((u16)(v & 0xFFFF));
        float a1 = b2f((u16)(v >> 16));
        int e = offs[d], e1 = offs[d + 1];
        for (; e + 4 <= e1; e += 4){
            int i0 = csr_src[e], i1 = csr_src[e + 1], i2 = csr_src[e + 2], i3 = csr_src[e + 3];
            u32 v0 = *reinterpret_cast<const u32*>(hw + i0 * HD + f0);
            u32 v1 = *reinterpret_cast<const u32*>(hw + i1 * HD + f0);
            u32 v2 = *reinterpret_cast<const u32*>(hw + i2 * HD + f0);
            u32 v3 = *reinterpret_cast<const u32*>(hw + i3 * HD + f0);
            a0 += b2f((u16)(v0 & 0xFFFF)); a1 += b2f((u16)(v0 >> 16));
            a0 += b2f((u16)(v1 & 0xFFFF)); a1 += b2f((u16)(v1 >> 16));
            a0 += b2f((u16)(v2 & 0xFFFF)); a1 += b2f((u16)(v2 >> 16));
            a0 += b2f((u16)(v3 & 0xFFFF)); a1 += b2f((u16)(v3 >> 16));
        }
        for (; e < e1; e++){
            int s = csr_src[e];
            u32 vv = *reinterpret_cast<const u32*>(hw + s * HD + f0);
            a0 += b2f((u16)(vv & 0xFFFF));
            a1 += b2f((u16)(vv >> 16));
        }
        a0 = a0 * di + b0;
        a1 = a1 * di + b1;
        u32 o = ((u32)f2b(a1) << 16) | (u32)f2b(a0);
        *reinterpret_cast<u32*>(agg + d * HD + f0) = o;
        s0 += a0; s1 += a1; q0 += a0 * a0; q1 += a1 * a1;
    }

    redS[wv][f0] = s0; redS[wv][f0 + 1] = s1;
    redQ[wv][f0] = q0; redQ[wv][f0 + 1] = q1;
    __syncthreads();
    if (tid < HD){
        float ts = redS[0][tid] + redS[1][tid] + redS[2][tid] + redS[3][tid];
        float tq = redQ[0][tid] + redQ[1][tid] + redQ[2][tid] + redQ[3][tid];
        atomicAdd(&sums[tid], ts);
        atomicAdd(&sums[HD + tid], tq);
    }
}

__global__ void k_bnprep(const float* __restrict__ sums, const float* __restrict__ gamma,
                         const float* __restrict__ beta, float* __restrict__ bn){
    int f = threadIdx.x;
    if (f >= HD) return;
    float mu = sums[f] / (float)NN;
    float var = sums[HD + f] / (float)NN - mu * mu;
    float inv = rsqrtf(var + 1e-5f);
    float a = gamma[f] * inv;
    bn[f] = a;
    bn[HD + f] = beta[f] - mu * a;
}

// ---------------- fused BN-apply + head: hA = BN(agg); out += hA @ W_out[row0:row0+128] ----------------
__launch_bounds__(256)
__global__ void k_bnhead(const u16* __restrict__ agg, const float* __restrict__ bn,
                         const float* __restrict__ wout, float* __restrict__ out,
                         u16* __restrict__ hA, int row0){
    __shared__ float wl[HD * NC]; // 20KB
    __shared__ float A[HD];
    __shared__ float C[HD];
    int tid = threadIdx.x;
    for (int i = tid; i < HD * NC; i += 256) wl[i] = wout[row0 * NC + i];
    if (tid < HD){ A[tid] = bn[tid]; C[tid] = bn[HD + tid]; }
    __syncthreads();
    int n = blockIdx.x * 256 + tid;
    if (n >= NN) return;
    float* orw = out + (size_t)n * NC;
    f32x4 acc[10];
    #pragma unroll
    for (int q = 0; q < 10; q++) acc[q] = reinterpret_cast<const f32x4*>(orw)[q];
    #pragma unroll
    for (int k8 = 0; k8 < HD / 8; k8++){
        uint4 v = reinterpret_cast<const uint4*>(agg + (size_t)n * HD)[k8];
        const u16* pv = (const u16*)&v;
        uint4 ov;
        u16* po = (u16*)&ov;
        #pragma unroll
        for (int t = 0; t < 8; t++){
            int f = k8 * 8 + t;
            float xv = b2f(pv[t]) * A[f] + C[f];
            po[t] = f2b(xv);
            const f32x4* wr = reinterpret_cast<const f32x4*>(&wl[f * NC]);
            #pragma unroll
            for (int q = 0; q < 10; q++) acc[q] += xv * wr[q];
        }
        reinterpret_cast<uint4*>(hA + (size_t)n * HD)[k8] = ov;
    }
    #pragma unroll
    for (int q = 0; q < 10; q++) reinterpret_cast<f32x4*>(orw)[q] = acc[q];
}

// ---------------- launch ----------------
extern "C" void kernel_launch(void* const* d_in, const int* in_sizes, int n_in,
                              void* d_out, int out_size, void* d_ws, size_t ws_size,
                              hipStream_t stream){
    const float* x      = (const float*)d_in[0];
    const float* Ws     = (const float*)d_in[1];
    const float* bs     = (const float*)d_in[2];
    const float* gammas = (const float*)d_in[3];
    const float* betas  = (const float*)d_in[4];
    const float* W_out  = (const float*)d_in[5];
    const float* b_out  = (const float*)d_in[6];
    const int*   ei     = (const int*)d_in[7];
    const int* src = ei;
    const int* dst = ei + NE;
    float* out = (float*)d_out;

    char* ws = (char*)d_ws;
    size_t off = 0;
    auto alloc = [&](size_t bytes) -> char* {
        char* p = ws + off;
        off += (bytes + 255) & ~(size_t)255;
        return p;
    };
    u16*   hA       = (u16*)alloc((size_t)NN * HD * 2);
    u16*   hw       = (u16*)alloc((size_t)NN * HD * 2);
    u16*   aggb     = (u16*)alloc((size_t)NN * HD * 2);  // aliased: bucket buffer lives here pre-loop
    u16*   wt       = (u16*)alloc((size_t)NL * HD * HD * 2);
    float* dinv     = (float*)alloc((size_t)NN * 4);
    int*   offs     = (int*)alloc((size_t)(NN + 1) * 4);
    int*   gcur     = (int*)alloc((size_t)NBK * 4);
    int*   ebase    = (int*)alloc((size_t)NBK * 4);
    int*   csr_src  = (int*)alloc((size_t)NE * 4);
    float* stats    = (float*)alloc((size_t)NL * 2 * HD * 4);
    float* bn       = (float*)alloc((size_t)2 * HD * 4);

    uint2* bb = (uint2*)aggb; // 196*9216*8 = 14.45 MB <= 25.6 MB; dead before layer loop

    hipMemsetAsync(gcur, 0, (size_t)NBK * 4, stream);
    hipMemsetAsync(stats, 0, (size_t)NL * 2 * HD * 4, stream);

    k_conv_w<<<(NL * HD * HD + 255) / 256, 256, 0, stream>>>(Ws, wt);
    k_bin<<<NBINBLK, 256, 0, stream>>>(src, dst, gcur, bb);
    k_bscan<<<1, 64, 0, stream>>>(gcur, ebase, offs);
    k_csr<<<NBK, 512, 0, stream>>>(gcur, ebase, bb, csr_src, offs, dinv);

    k_convhead<<<(NN + 255) / 256, 256, 0, stream>>>(x, W_out, b_out, out, hA);

    for (int l = 0; l < NL; l++){
        k_gemm<<<(NN + 63) / 64, 256, 0, stream>>>(hA, wt + (size_t)l * HD * HD, dinv, hw);
        k_agg<<<2048, 256, 0, stream>>>(hw, offs, csr_src, dinv,
                                        bs + (size_t)l * HD, aggb, stats + (size_t)l * 2 * HD);
        k_bnprep<<<1, 128, 0, stream>>>(stats + (size_t)l * 2 * HD,
                                        gammas + (size_t)l * HD, betas + (size_t)l * HD, bn);
        k_bnhead<<<(NN + 255) / 256, 256, 0, stream>>>(aggb, bn, W_out, out, hA,
                                                       HD + l * HD);
    }
}

// Round 5
// 560.291 us; speedup vs baseline: 1.4891x; 1.0815x over previous
//
#include <hip/hip_runtime.h>

#define NN 100000
#define NE 1600000
#define HD 128
#define NL 3
#define NC 40

#define NBK 196     // dst buckets (512 nodes each; 196*512 = 100352 >= NN)
#define NPB 512     // nodes per bucket
#define BSH 9       // bucket shift (dst >> 9)
#define CAP 9216    // per-bucket raw edge capacity (mean 8163, +11 sigma)
#define PCAP 13312  // per-bucket padded CSR capacity: 512*8 + CAP = 13312 exact worst case
#define EPB 2000    // edges per bin block
#define NBINBLK 800 // 800 * 2000 = NE

typedef unsigned int u32;
typedef unsigned short u16;
typedef __attribute__((ext_vector_type(8))) short short8;
typedef __attribute__((ext_vector_type(4))) float f32x4;

__device__ __forceinline__ float b2f(u16 h){
    union{u32 u; float f;} v; v.u = ((u32)h) << 16; return v.f;
}
__device__ __forceinline__ u16 f2b(float f){
    union{float f; u32 u;} v; v.f = f;
    u32 u = v.u;
    u32 r = (u + 0x7FFFu + ((u >> 16) & 1u)) >> 16;
    return (u16)r;
}

// ---------------- weight conversion ----------------
// Wt[l][n][k] = W[l][k][n]  (transposed, bf16)
__global__ void k_conv_w(const float* __restrict__ Ws, u16* __restrict__ wt){
    int i = blockIdx.x * blockDim.x + threadIdx.x;
    if (i >= NL * HD * HD) return;
    int l = i / (HD * HD);
    int r = i % (HD * HD);
    int n = r / HD;
    int k = r % HD;
    wt[i] = f2b(Ws[l * HD * HD + k * HD + n]);
}

// ---------------- x -> bf16 + first head pass: out = b_out + x @ W_out[0:128] ----------------
__launch_bounds__(256)
__global__ void k_convhead(const float* __restrict__ x, const float* __restrict__ wout,
                           const float* __restrict__ bout, float* __restrict__ out,
                           u16* __restrict__ hA){
    __shared__ float wl[HD * NC]; // rows 0..127 of W_out
    __shared__ float bl[NC];
    int tid = threadIdx.x;
    for (int i = tid; i < HD * NC; i += 256) wl[i] = wout[i];
    if (tid < NC) bl[tid] = bout[tid];
    __syncthreads();
    int n = blockIdx.x * 256 + tid;
    if (n >= NN) return;
    f32x4 acc[10];
    #pragma unroll
    for (int q = 0; q < 10; q++) acc[q] = *reinterpret_cast<const f32x4*>(&bl[q * 4]);
    const float* xr = x + (size_t)n * HD;
    #pragma unroll
    for (int k8 = 0; k8 < HD / 8; k8++){
        float4 v0 = reinterpret_cast<const float4*>(xr)[k8 * 2];
        float4 v1 = reinterpret_cast<const float4*>(xr)[k8 * 2 + 1];
        float xs[8] = {v0.x, v0.y, v0.z, v0.w, v1.x, v1.y, v1.z, v1.w};
        uint4 ov;
        u16* po = (u16*)&ov;
        #pragma unroll
        for (int t = 0; t < 8; t++){
            int f = k8 * 8 + t;
            po[t] = f2b(xs[t]);
            const f32x4* wr = reinterpret_cast<const f32x4*>(&wl[f * NC]);
            #pragma unroll
            for (int q = 0; q < 10; q++) acc[q] += xs[t] * wr[q];
        }
        reinterpret_cast<uint4*>(hA + (size_t)n * HD)[k8] = ov;
    }
    float* orw = out + (size_t)n * NC;
    #pragma unroll
    for (int q = 0; q < 10; q++) reinterpret_cast<f32x4*>(orw)[q] = acc[q];
}

// ---------------- pass 1: bin edges by dst bucket, coalesced grouped writes ----------------
__launch_bounds__(256)
__global__ void k_bin(const int* __restrict__ src, const int* __restrict__ dst,
                      int* __restrict__ gcur, uint2* __restrict__ bb){
    __shared__ int hist[NBK];
    __shared__ int lbase[NBK];
    __shared__ int gbase[NBK];
    __shared__ int cur[NBK];
    __shared__ uint2 stage[EPB]; // 16 KB
    int tid = threadIdx.x;
    int e0 = blockIdx.x * EPB;
    for (int i = tid; i < NBK; i += 256) hist[i] = 0;
    __syncthreads();
    for (int k = tid; k < EPB; k += 256){
        int d = dst[e0 + k];
        atomicAdd(&hist[d >> BSH], 1);
    }
    __syncthreads();
    if (tid == 0){
        int run = 0;
        for (int b = 0; b < NBK; b++){ lbase[b] = run; cur[b] = run; run += hist[b]; }
    }
    __syncthreads();
    if (tid < NBK) gbase[tid] = atomicAdd(&gcur[tid], hist[tid]);
    __syncthreads();
    for (int k = tid; k < EPB; k += 256){
        int s = src[e0 + k], d = dst[e0 + k];
        int pos = atomicAdd(&cur[d >> BSH], 1);
        stage[pos] = make_uint2((u32)s, (u32)d);
    }
    __syncthreads();
    for (int k = tid; k < EPB; k += 256){
        uint2 sd = stage[k];
        int b = (int)(sd.y >> BSH);
        int g = gbase[b] + (k - lbase[b]);
        if (g < CAP) bb[(size_t)b * CAP + g] = sd;
    }
}

// ---------------- pass 2: per-bucket padded CSR build, all global I/O coalesced ----------------
// Per node layout: [self, neighbors..., pad(NN)...] length rounded up to multiple of 8.
// offs[n] = start, oend[n] = start + padded-length (true per-node end; avoids bucket-gap).
__launch_bounds__(512)
__global__ void k_csr(const int* __restrict__ gcur, const uint2* __restrict__ bb,
                      int* __restrict__ csr_src, int* __restrict__ offs,
                      int* __restrict__ oend, float* __restrict__ dinv){
    __shared__ int hist[NPB];
    __shared__ int cur[NPB];
    __shared__ int wsum[8];
    __shared__ int totp_s;
    __shared__ int lcsr[PCAP]; // 52 KB
    int tid = threadIdx.x;
    int b = blockIdx.x;
    int cnt_b = gcur[b]; if (cnt_b > CAP) cnt_b = CAP;
    const uint2* eb = bb + (size_t)b * CAP;
    hist[tid] = 0;
    __syncthreads();
    for (int k = tid; k < cnt_b; k += 512)
        atomicAdd(&hist[eb[k].y & (NPB - 1)], 1);
    __syncthreads();
    int cnt = hist[tid];
    int ps = (1 + cnt + 7) & ~7;   // padded slots incl self
    int lane = tid & 63, w = tid >> 6;
    int incl = ps;
    #pragma unroll
    for (int dlt = 1; dlt < 64; dlt <<= 1){
        int t = __shfl_up(incl, dlt);
        if (lane >= dlt) incl += t;
    }
    if (lane == 63) wsum[w] = incl;
    __syncthreads();
    if (tid == 0){
        int run = 0;
        #pragma unroll
        for (int j = 0; j < 8; j++){ int t = wsum[j]; wsum[j] = run; run += t; }
        totp_s = run;
    }
    __syncthreads();
    int excl = wsum[w] + incl - ps;
    int n = b * NPB + tid;
    offs[n] = b * PCAP + excl;
    oend[n] = b * PCAP + excl + ps;
    if (n < NN) dinv[n] = rsqrtf((float)(cnt + 1));
    cur[tid] = excl + 1;           // neighbors start after self slot
    int totp = totp_s;
    __syncthreads();
    for (int k = tid; k < totp; k += 512) lcsr[k] = NN;   // pad -> zero row
    __syncthreads();
    lcsr[excl] = (n < NN) ? n : NN;    // self edge (tail nodes -> zero row)
    __syncthreads();
    for (int k = tid; k < cnt_b; k += 512){
        uint2 sd = eb[k];
        int pos = atomicAdd(&cur[sd.y & (NPB - 1)], 1);
        lcsr[pos] = (int)sd.x;
    }
    __syncthreads();
    for (int k = tid; k < totp; k += 512)
        csr_src[b * PCAP + k] = lcsr[k];
}

// ---------------- dense GEMM: hw = (h @ W) * dinv[row]  (MFMA bf16) ----------------
__launch_bounds__(256)
__global__ void k_gemm(const u16* __restrict__ h, const u16* __restrict__ wt,
                       const float* __restrict__ dinv, u16* __restrict__ out){
    __shared__ u16 wlds[HD * HD]; // 32KB, XOR-swizzled in 16B units
    int tid = threadIdx.x;
    {
        const uint4* g = reinterpret_cast<const uint4*>(wt);
        #pragma unroll
        for (int i = 0; i < 8; i++){
            int lin16 = tid + 256 * i;
            uint4 v = g[lin16];
            int c = lin16 >> 4;
            int addr16 = lin16 ^ (c & 7);
            reinterpret_cast<uint4*>(wlds)[addr16] = v;
        }
    }
    __syncthreads();

    int wv = tid >> 6, lane = tid & 63;
    int row_base = blockIdx.x * 64 + wv * 16;
    int arow = row_base + (lane & 15);
    if (arow >= NN) arow = NN - 1;
    int koff = (lane >> 4) * 8;

    f32x4 acc[8];
    #pragma unroll
    for (int t = 0; t < 8; t++) acc[t] = (f32x4){0.f, 0.f, 0.f, 0.f};

    #pragma unroll
    for (int kk = 0; kk < 4; kk++){
        short8 a = *reinterpret_cast<const short8*>(h + arow * HD + kk * 32 + koff);
        #pragma unroll
        for (int ct = 0; ct < 8; ct++){
            int c = ct * 16 + (lane & 15);
            int addr16 = (c * 16 + kk * 4 + (koff >> 3)) ^ (c & 7);
            short8 b = *reinterpret_cast<const short8*>(wlds + addr16 * 8);
            acc[ct] = __builtin_amdgcn_mfma_f32_16x16x32_bf16(a, b, acc[ct], 0, 0, 0);
        }
    }

    int drow = row_base + (lane >> 4) * 4;
    int dcol = lane & 15;
    float dv[4];
    #pragma unroll
    for (int r = 0; r < 4; r++){
        int rr = drow + r;
        dv[r] = dinv[rr < NN ? rr : NN - 1];
    }
    #pragma unroll
    for (int ct = 0; ct < 8; ct++){
        #pragma unroll
        for (int r = 0; r < 4; r++){
            int rr = drow + r;
            if (rr < NN) out[rr * HD + ct * 16 + dcol] = f2b(acc[ct][r] * dv[r]);
        }
    }
}

// ---------------- aggregation + BN stats ----------------
// wave per 16 contiguous nodes; padded CSR (self + pad included, multiple of 8)
// agg[d] = dinv[d] * sum(rows) + bias; deep-pipelined row gather
__launch_bounds__(256)
__global__ void k_agg(const u16* __restrict__ hw, const int* __restrict__ offs,
                      const int* __restrict__ oend, const int* __restrict__ csr_src,
                      const float* __restrict__ dinv, const float* __restrict__ bias,
                      u16* __restrict__ agg, float* __restrict__ sums){
    __shared__ float redS[4][HD];
    __shared__ float redQ[4][HD];
    int tid = threadIdx.x;
    int lane = tid & 63;
    int wv = tid >> 6;
    int f0 = lane * 2;
    float b0 = bias[f0], b1 = bias[f0 + 1];
    float s0 = 0.f, s1 = 0.f, q0 = 0.f, q1 = 0.f;
    int n0 = (blockIdx.x * 4 + wv) * 16;
    const u32* hw32 = reinterpret_cast<const u32*>(hw); // row = 64 u32, lane offset = lane

    for (int k = 0; k < 16; k++){
        int n = n0 + k;
        if (n >= NN) break;
        float a0 = 0.f, a1 = 0.f, c0 = 0.f, c1 = 0.f;
        int e = offs[n], e1 = oend[n];
        int rem = e1 - e;
        while (rem > 0){
            int win = rem < 64 ? rem : 64;
            int idxv = csr_src[e + lane];       // one coalesced load stages up to 64 indices
            int nch = win >> 3;                 // chunks of 8 (win is multiple of 8)
            u32 va[8], vb[8];

            #pragma unroll
            for (int j = 0; j < 8; j++){
                u32 uid = (u32)__builtin_amdgcn_readlane(idxv, j);
                va[j] = hw32[(size_t)(uid << 6) + (u32)lane];
            }
            for (int c = 1; c < nch; c++){
                if (c & 1){
                    #pragma unroll
                    for (int j = 0; j < 8; j++){
                        u32 uid = (u32)__builtin_amdgcn_readlane(idxv, c * 8 + j);
                        vb[j] = hw32[(size_t)(uid << 6) + (u32)lane];
                    }
                    #pragma unroll
                    for (int j = 0; j < 8; j++){
                        union{u32 u; float f;} L, H;
                        L.u = va[j] << 16; H.u = va[j] & 0xFFFF0000u;
                        a0 += L.f; a1 += H.f;
                    }
                } else {
                    #pragma unroll
                    for (int j = 0; j < 8; j++){
                        u32 uid = (u32)__builtin_amdgcn_readlane(idxv, c * 8 + j);
                        va[j] = hw32[(size_t)(uid << 6) + (u32)lane];
                    }
                    #pragma unroll
                    for (int j = 0; j < 8; j++){
                        union{u32 u; float f;} L, H;
                        L.u = vb[j] << 16; H.u = vb[j] & 0xFFFF0000u;
                        c0 += L.f; c1 += H.f;
                    }
                }
            }
            if (nch & 1){
                #pragma unroll
                for (int j = 0; j < 8; j++){
                    union{u32 u; float f;} L, H;
                    L.u = va[j] << 16; H.u = va[j] & 0xFFFF0000u;
                    a0 += L.f; a1 += H.f;
                }
            } else {
                #pragma unroll
                for (int j = 0; j < 8; j++){
                    union{u32 u; float f;} L, H;
                    L.u = vb[j] << 16; H.u = vb[j] & 0xFFFF0000u;
                    c0 += L.f; c1 += H.f;
                }
            }
            e += win; rem -= win;
        }
        float di = dinv[n];
        a0 = (a0 + c0) * di + b0;
        a1 = (a1 + c1) * di + b1;
        u32 o = ((u32)f2b(a1) << 16) | (u32)f2b(a0);
        *reinterpret_cast<u32*>(agg + (size_t)n * HD + f0) = o;
        s0 += a0; s1 += a1; q0 += a0 * a0; q1 += a1 * a1;
    }

    redS[wv][f0] = s0; redS[wv][f0 + 1] = s1;
    redQ[wv][f0] = q0; redQ[wv][f0 + 1] = q1;
    __syncthreads();
    if (tid < HD){
        float ts = redS[0][tid] + redS[1][tid] + redS[2][tid] + redS[3][tid];
        float tq = redQ[0][tid] + redQ[1][tid] + redQ[2][tid] + redQ[3][tid];
        atomicAdd(&sums[tid], ts);
        atomicAdd(&sums[HD + tid], tq);
    }
}

__global__ void k_bnprep(const float* __restrict__ sums, const float* __restrict__ gamma,
                         const float* __restrict__ beta, float* __restrict__ bn){
    int f = threadIdx.x;
    if (f >= HD) return;
    float mu = sums[f] / (float)NN;
    float var = sums[HD + f] / (float)NN - mu * mu;
    float inv = rsqrtf(var + 1e-5f);
    float a = gamma[f] * inv;
    bn[f] = a;
    bn[HD + f] = beta[f] - mu * a;
}

// ---------------- fused BN-apply + head: hA = BN(agg); out += hA @ W_out[row0:row0+128] ----------------
__launch_bounds__(256)
__global__ void k_bnhead(const u16* __restrict__ agg, const float* __restrict__ bn,
                         const float* __restrict__ wout, float* __restrict__ out,
                         u16* __restrict__ hA, int row0){
    __shared__ float wl[HD * NC]; // 20KB
    __shared__ float A[HD];
    __shared__ float C[HD];
    int tid = threadIdx.x;
    for (int i = tid; i < HD * NC; i += 256) wl[i] = wout[row0 * NC + i];
    if (tid < HD){ A[tid] = bn[tid]; C[tid] = bn[HD + tid]; }
    __syncthreads();
    int n = blockIdx.x * 256 + tid;
    if (n >= NN) return;
    float* orw = out + (size_t)n * NC;
    f32x4 acc[10];
    #pragma unroll
    for (int q = 0; q < 10; q++) acc[q] = reinterpret_cast<const f32x4*>(orw)[q];
    #pragma unroll
    for (int k8 = 0; k8 < HD / 8; k8++){
        uint4 v = reinterpret_cast<const uint4*>(agg + (size_t)n * HD)[k8];
        const u16* pv = (const u16*)&v;
        uint4 ov;
        u16* po = (u16*)&ov;
        #pragma unroll
        for (int t = 0; t < 8; t++){
            int f = k8 * 8 + t;
            float xv = b2f(pv[t]) * A[f] + C[f];
            po[t] = f2b(xv);
            const f32x4* wr = reinterpret_cast<const f32x4*>(&wl[f * NC]);
            #pragma unroll
            for (int q = 0; q < 10; q++) acc[q] += xv * wr[q];
        }
        reinterpret_cast<uint4*>(hA + (size_t)n * HD)[k8] = ov;
    }
    #pragma unroll
    for (int q = 0; q < 10; q++) reinterpret_cast<f32x4*>(orw)[q] = acc[q];
}

// ---------------- launch ----------------
extern "C" void kernel_launch(void* const* d_in, const int* in_sizes, int n_in,
                              void* d_out, int out_size, void* d_ws, size_t ws_size,
                              hipStream_t stream){
    const float* x      = (const float*)d_in[0];
    const float* Ws     = (const float*)d_in[1];
    const float* bs     = (const float*)d_in[2];
    const float* gammas = (const float*)d_in[3];
    const float* betas  = (const float*)d_in[4];
    const float* W_out  = (const float*)d_in[5];
    const float* b_out  = (const float*)d_in[6];
    const int*   ei     = (const int*)d_in[7];
    const int* src = ei;
    const int* dst = ei + NE;
    float* out = (float*)d_out;

    char* ws = (char*)d_ws;
    size_t off = 0;
    auto alloc = [&](size_t bytes) -> char* {
        char* p = ws + off;
        off += (bytes + 255) & ~(size_t)255;
        return p;
    };
    u16*   hA       = (u16*)alloc((size_t)NN * HD * 2);
    u16*   hw       = (u16*)alloc((size_t)(NN + 1) * HD * 2);  // +1 zero row for CSR padding
    u16*   aggb     = (u16*)alloc((size_t)NN * HD * 2);        // aliased: bucket buffer pre-loop
    u16*   wt       = (u16*)alloc((size_t)NL * HD * HD * 2);
    float* dinv     = (float*)alloc((size_t)NN * 4);
    int*   offs     = (int*)alloc((size_t)(NBK * NPB) * 4);
    int*   oend     = (int*)alloc((size_t)(NBK * NPB) * 4);
    int*   gcur     = (int*)alloc((size_t)NBK * 4);
    int*   csr_src  = (int*)alloc(((size_t)NBK * PCAP + 256) * 4);
    float* stats    = (float*)alloc((size_t)NL * 2 * HD * 4);
    float* bn       = (float*)alloc((size_t)2 * HD * 4);

    uint2* bb = (uint2*)aggb; // 196*9216*8 = 14.45 MB <= 25.6 MB; dead before layer loop

    hipMemsetAsync(gcur, 0, (size_t)NBK * 4, stream);
    hipMemsetAsync(stats, 0, (size_t)NL * 2 * HD * 4, stream);
    hipMemsetAsync(hw + (size_t)NN * HD, 0, HD * 2, stream);   // zero row NN

    k_conv_w<<<(NL * HD * HD + 255) / 256, 256, 0, stream>>>(Ws, wt);
    k_bin<<<NBINBLK, 256, 0, stream>>>(src, dst, gcur, bb);
    k_csr<<<NBK, 512, 0, stream>>>(gcur, bb, csr_src, offs, oend, dinv);

    k_convhead<<<(NN + 255) / 256, 256, 0, stream>>>(x, W_out, b_out, out, hA);

    for (int l = 0; l < NL; l++){
        k_gemm<<<(NN + 63) / 64, 256, 0, stream>>>(hA, wt + (size_t)l * HD * HD, dinv, hw);
        k_agg<<<(NN + 63) / 64, 256, 0, stream>>>(hw, offs, oend, csr_src, dinv,
                                                  bs + (size_t)l * HD, aggb,
                                                  stats + (size_t)l * 2 * HD);
        k_bnprep<<<1, 128, 0, stream>>>(stats + (size_t)l * 2 * HD,
                                        gammas + (size_t)l * HD, betas + (size_t)l * HD, bn);
        k_bnhead<<<(NN + 255) / 256, 256, 0, stream>>>(aggb, bn, W_out, out, hA,
                                                       HD + l * HD);
    }
}